// Round 20
// baseline (87.565 us; speedup 1.0000x reference)
//
#include <hip/hip_runtime.h>
#include <hip/hip_bf16.h>

// MixMIL — R20: SINGLE fused kernel. R19 persistent-wave body + last-block
// finalization (statsout kernel + launch gap deleted).
// Shapes: I=512000, Q=128, P=1, S=8, N=4000. x f32, betas f32, seg int32 sorted.
//
// Algebra: accumulate with raw beta_z; b = rms(beta_z) applied only at the end.
// Max-free softmax (|u|max ~62 << 88; R15-R19-verified).
// 3-MFMA hi/lo bf16 split, hardware cvts (R17, absmax 1.56e-2).
//
// R20 change vs R19 (61.0us; fused loop at HBM service rate, schedule levers
// exhausted; remaining removable cost = statsout kernel + launch gap ~4us):
//  - last-block-done finalization: block end -> __syncthreads -> t0
//    __threadfence (flush xmil past non-coherent per-XCD L2, G16) +
//    device-scope atomicAdd on ws counter (m20) -> last block fences (acquire)
//    and runs the stats+output body itself. Counter reset per call via
//    hipMemsetAsync (graph-legal). Deterministic output regardless of which
//    block finalizes. Empty-bag waves no longer early-return (uniform barrier).

#define QDIM 128
#define C8 8

typedef __attribute__((ext_vector_type(8))) short s8v;
typedef __attribute__((ext_vector_type(4))) float f4v;

// hi/lo bf16 split via hardware conversions
__device__ __forceinline__ void split8(const float xs[8], s8v& AH, s8v& AL) {
#pragma unroll
    for (int j = 0; j < 8; ++j) {
        const float xv = xs[j];
        const __hip_bfloat16 hb = __float2bfloat16(xv);       // hw cvt (RNE)
        const float hf = __bfloat162float(hb);                // shift
        const __hip_bfloat16 lb = __float2bfloat16(xv - hf);  // exact residual cvt
        unsigned short hr, lr;
        __builtin_memcpy(&hr, &hb, 2);
        __builtin_memcpy(&lr, &lb, 2);
        AH[j] = (short)hr;
        AL[j] = (short)lr;
    }
}

__global__ __launch_bounds__(256) void mixmil_fused(
    const float* __restrict__ x,
    const float* __restrict__ bu,
    const float* __restrict__ bz,
    const int*   __restrict__ seg,
    int I, int N, int bstride,   // bstride = 4*gridDim
    float* __restrict__ xmil,    // [N,8] ws
    int*   __restrict__ counter, // ws, memset to 0 before launch
    float* __restrict__ out)     // [N*8] final output
{
    // 4 waves x 2 buffers x 8KB = 64KB
    __shared__ float XT[4 * 2 * 2048];

    const int t    = threadIdx.x;
    const int lane = t & 63;
    const int wv   = t >> 6;

    const int b0 = blockIdx.x * 4 + wv;          // first bag (< 2000 < N always)
    const int b1 = b0 + bstride;                 // second bag (may be >= N)

    // In-wave bounds: lanes 0-3 binary-search seg for j = b0, b0+1, b1, b1+1.
    int jq = N;
    if (lane == 0) jq = b0;
    else if (lane == 1) jq = b0 + 1;
    else if (lane == 2) jq = (b1 < N) ? b1 : N;
    else if (lane == 3) jq = (b1 + 1 < N) ? (b1 + 1) : N;
    int slo = 0, shi = I;
    while (slo < shi) {
        const int mid = (slo + shi) >> 1;
        if (seg[mid] < jq) slo = mid + 1; else shi = mid;
    }
    const int lo0 = __shfl(slo, 0);
    const int hi0 = __shfl(slo, 1);
    int lo1 = 0, hi1 = 0;
    if (b1 < N) { lo1 = __shfl(slo, 2); hi1 = __shfl(slo, 3); }

    const int nt0 = (hi0 - lo0 + 15) >> 4;
    const int nt1 = (hi1 - lo1 + 15) >> 4;
    const int total = nt0 + nt1;

    // Empty-bag zero writes (finalize below only runs for bags with >=1 tile).
    if (lane < 8) {
        if (nt0 == 0) xmil[(size_t)b0 * 8 + lane] = 0.f;
        if (b1 < N && nt1 == 0) xmil[(size_t)b1 * 8 + lane] = 0.f;
    }

    if (total > 0) {
        // B fragments (weights), hi/lo split. B[k][n]: n=lane&15, k=(lane>>4)*8+j.
        const int bn  = lane & 15;
        const int bkg = lane >> 4;
        s8v BH[4], BL[4];
        const float* wcol = (bn < 8) ? (bu + bn) : (bz + (bn - 8));
#pragma unroll
        for (int kc = 0; kc < 4; ++kc) {
            float ws[8];
#pragma unroll
            for (int j = 0; j < 8; ++j)
                ws[j] = wcol[(size_t)(kc * 32 + bkg * 8 + j) * 8];
            split8(ws, BH[kc], BL[kc]);
        }

        float* const myXT = &XT[wv * 4096];
        const int rl  = lane >> 5;
        const int c4l = lane & 31;

#define CH_BASE(C) (((C) >= nt0) ? (lo1 + (((C) - nt0) << 4)) : (lo0 + ((C) << 4)))
#define CH_LIM(C)  (((C) >= nt0) ? hi1 : hi0)

#define STAGE(C)                                                               \
        {                                                                      \
            const int base_ = CH_BASE(C);                                      \
            const int lim_  = CH_LIM(C);                                       \
            float* dst_ = &myXT[((C) & 1) * 2048];                             \
            _Pragma("unroll")                                                  \
            for (int i = 0; i < 8; ++i) {                                      \
                const int r_ = i * 2 + rl;                                     \
                int grow_ = base_ + r_;                                        \
                if (grow_ >= lim_) grow_ = lim_ - 1;                           \
                const int c4g_ = c4l ^ (r_ & 7);                               \
                const float* src_ = x + (size_t)grow_ * QDIM + 4 * (size_t)c4g_; \
                __builtin_amdgcn_global_load_lds(                              \
                    (const __attribute__((address_space(1))) unsigned int*)src_, \
                    (__attribute__((address_space(3))) unsigned int*)          \
                        (dst_ + i * 256),                                      \
                    16, 0, 0);                                                 \
            }                                                                  \
        }

        float lsum = 0.f, asum = 0.f;

        const int am  = lane & 15;
        const int akg = lane >> 4;
        const int sw  = am & 7;

        STAGE(0);

        for (int c = 0; c < total; ++c) {
            if (c + 1 < total) {
                STAGE(c + 1);
                asm volatile("s_waitcnt vmcnt(8)" ::: "memory");
            } else {
                asm volatile("s_waitcnt vmcnt(0)" ::: "memory");
            }
            __builtin_amdgcn_sched_barrier(0);

            const float* buf = &myXT[(c & 1) * 2048];

            f4v acc = {0.f, 0.f, 0.f, 0.f};
#pragma unroll
            for (int kc = 0; kc < 4; ++kc) {
                const int c4a = kc * 8 + akg * 2;
                const float4 xa = *(const float4*)&buf[am * QDIM + 4 * ((c4a    ) ^ sw)];
                const float4 xb = *(const float4*)&buf[am * QDIM + 4 * ((c4a + 1) ^ sw)];
                const float xs[8] = {xa.x, xa.y, xa.z, xa.w, xb.x, xb.y, xb.z, xb.w};
                s8v AH, AL;
                split8(xs, AH, AL);
                acc = __builtin_amdgcn_mfma_f32_16x16x32_bf16(AH, BH[kc], acc, 0, 0, 0);
                acc = __builtin_amdgcn_mfma_f32_16x16x32_bf16(AH, BL[kc], acc, 0, 0, 0);
                acc = __builtin_amdgcn_mfma_f32_16x16x32_bf16(AL, BH[kc], acc, 0, 0, 0);
            }

            const int base = CH_BASE(c);
            const int lim  = CH_LIM(c);
            const int r0   = (lane >> 4) * 4;
#pragma unroll
            for (int i = 0; i < 4; ++i) {
                const float uv = acc[i];
                const float zv = __shfl_xor(uv, 8);
                const bool valid = (base + r0 + i) < lim;
                if ((lane & 15) < 8 && valid) {
                    const float e = __expf(uv);
                    lsum += e;
                    asum = fmaf(e, zv, asum);
                }
            }

            const bool fin0 = (c == nt0 - 1);
            const bool fin1 = (c == total - 1) && (nt1 > 0);
            if (fin0 || fin1) {
                float ls = lsum, as = asum;
                ls += __shfl_xor(ls, 16);
                as += __shfl_xor(as, 16);
                ls += __shfl_xor(ls, 32);
                as += __shfl_xor(as, 32);
                const int bag = fin0 ? b0 : b1;
                if (lane < 8)
                    xmil[(size_t)bag * 8 + lane] = as / ls;
                lsum = 0.f; asum = 0.f;
            }
        }
#undef STAGE
#undef CH_BASE
#undef CH_LIM
    }

    // ---- last-block-done finalization (replaces the statsout kernel) ----
    __shared__ int isLast;
    __syncthreads();                       // all 4 waves done with their bags
    if (t == 0) {
        __threadfence();                   // flush xmil writes device-wide
        const int old = atomicAdd(counter, 1);   // device-scope (m20)
        isLast = (old == (int)gridDim.x - 1) ? 1 : 0;
    }
    __syncthreads();
    if (!isLast) return;
    __threadfence();                       // acquire: see all blocks' xmil

    // stats + output (exact statsout body; xmil is L3-resident)
    double s[8], qq[8];
    float t2[8];
#pragma unroll
    for (int c = 0; c < 8; ++c) { s[c] = 0.0; qq[c] = 0.0; t2[c] = 0.f; }

    for (int r = t; r < N; r += 256) {
        const float* row = xmil + (size_t)r * 8;
#pragma unroll
        for (int c = 0; c < 8; ++c) {
            float v = row[c];
            s[c] += v;
            qq[c] += (double)v * (double)v;
        }
    }
    for (int r = t; r < QDIM; r += 256) {
        const float* row = bz + (size_t)r * 8;
#pragma unroll
        for (int c = 0; c < 8; ++c) { float v = row[c]; t2[c] = fmaf(v, v, t2[c]); }
    }

    for (int off = 32; off; off >>= 1) {
#pragma unroll
        for (int c = 0; c < 8; ++c) {
            s[c]  += __shfl_xor(s[c], off);
            qq[c] += __shfl_xor(qq[c], off);
            t2[c] += __shfl_xor(t2[c], off);
        }
    }

    __shared__ double S[4][8], QQ[4][8];
    __shared__ float T2[4][8];
    __shared__ float fb[8], fm[8], fr[8];
    const int w = t >> 6;
    if ((t & 63) == 0) {
#pragma unroll
        for (int c = 0; c < 8; ++c) { S[w][c] = s[c]; QQ[w][c] = qq[c]; T2[w][c] = t2[c]; }
    }
    __syncthreads();
    if (t < 8) {
        const int c = t;
        double ss = S[0][c] + S[1][c] + S[2][c] + S[3][c];
        double qs = QQ[0][c] + QQ[1][c] + QQ[2][c] + QQ[3][c];
        float  tt = T2[0][c] + T2[1][c] + T2[2][c] + T2[3][c];
        double mean = ss / (double)N;
        double var  = (qs - ss * ss / (double)N) / (double)(N - 1);
        fb[c] = sqrtf(tt / (float)QDIM);
        fm[c] = (float)mean;
        fr[c] = (float)(1.0 / sqrt(var));
    }
    __syncthreads();

    const int tot = N * C8;
    for (int e = t; e < tot; e += 256) {
        const int c = e & 7;
        out[e] = fb[c] * (xmil[e] - fm[c]) * fr[c];
    }
}

extern "C" void kernel_launch(void* const* d_in, const int* in_sizes, int n_in,
                              void* d_out, int out_size, void* d_ws, size_t ws_size,
                              hipStream_t stream) {
    const float* x  = (const float*)d_in[0];
    const float* bu = (const float*)d_in[1];
    const float* bz = (const float*)d_in[2];
    const int*   sg = (const int*)d_in[3];   // sorted bag ids (int32)

    const int I = in_sizes[0] / QDIM;        // 512000
    const int N = out_size / C8;             // 4000 bags

    // grid: 2 bags per wave -> ceil(N/8) blocks; all co-resident (<=512).
    const int nblk = (N + 7) / 8;            // 500
    const int bstride = nblk * 4;            // 2000

    // ws layout: xmil[N*8] | counter[1]
    float* xmil    = (float*)d_ws;
    int*   counter = (int*)(xmil + (size_t)N * C8);

    hipMemsetAsync(counter, 0, sizeof(int), stream);   // graph-legal reset

    mixmil_fused<<<nblk, 256, 0, stream>>>(x, bu, bz, sg, I, N, bstride,
                                           xmil, counter, (float*)d_out);
}

// Round 23
// 71.598 us; speedup vs baseline: 1.2230x; 1.2230x over previous
//
#include <hip/hip_runtime.h>
#include <hip/hip_bf16.h>

// MixMIL — R23 = R21 resubmitted again (R21 and R22 benches both died to the
// same unresponsive container before running; the kernel has never been
// measured).
// R19 structure (2 kernels, no atomic finale) with 32-row chunks: 2
// waves/block, per-wave 2x16KB LDS dbuf, 16 KB sequential HBM bursts per
// stream, vmcnt(16) counted wait.
// Shapes: I=512000, Q=128, P=1, S=8, N=4000. x f32, betas f32, seg int32 sorted.
//
// Algebra: accumulate with raw beta_z; b = rms(beta_z) applied only at the end.
// Max-free softmax (|u|max ~62 << 88; R15-R19-verified).
// 3-MFMA hi/lo bf16 split, hardware cvts (R17, absmax 1.56e-2).
//
// R20 (atomic last-block finale + per-replay memset) regressed 61->88us.
// R21/R22/R23 tests the one untested mechanism: HBM request granularity.
// 16-row chunks (8KB) -> 32-row chunks (16KB): half the chunk-boundary
// events, twice the sequential burst length per wave-stream. Schedule
// unchanged (R16/R18 proved schedule is not the lever).

#define QDIM 128
#define C8 8

typedef __attribute__((ext_vector_type(8))) short s8v;
typedef __attribute__((ext_vector_type(4))) float f4v;

// hi/lo bf16 split via hardware conversions
__device__ __forceinline__ void split8(const float xs[8], s8v& AH, s8v& AL) {
#pragma unroll
    for (int j = 0; j < 8; ++j) {
        const float xv = xs[j];
        const __hip_bfloat16 hb = __float2bfloat16(xv);       // hw cvt (RNE)
        const float hf = __bfloat162float(hb);                // shift
        const __hip_bfloat16 lb = __float2bfloat16(xv - hf);  // exact residual cvt
        unsigned short hr, lr;
        __builtin_memcpy(&hr, &hb, 2);
        __builtin_memcpy(&lr, &lb, 2);
        AH[j] = (short)hr;
        AL[j] = (short)lr;
    }
}

__global__ __launch_bounds__(128) void mixmil_fused(
    const float* __restrict__ x,
    const float* __restrict__ bu,
    const float* __restrict__ bz,
    const int*   __restrict__ seg,
    int I, int N, int bstride,   // bstride = 2*gridDim
    float* __restrict__ xmil)    // [N,8]
{
    // 2 waves x 2 buffers x 16KB = 64KB
    __shared__ float XT[2 * 2 * 4096];

    const int t    = threadIdx.x;
    const int lane = t & 63;
    const int wv   = t >> 6;

    const int b0 = blockIdx.x * 2 + wv;          // first bag
    const int b1 = b0 + bstride;                 // second bag (may be >= N)
    if (b0 >= N) return;

    // In-wave bounds: lanes 0-3 binary-search seg for j = b0, b0+1, b1, b1+1.
    int jq = N;
    if (lane == 0) jq = b0;
    else if (lane == 1) jq = b0 + 1;
    else if (lane == 2) jq = (b1 < N) ? b1 : N;
    else if (lane == 3) jq = (b1 + 1 < N) ? (b1 + 1) : N;
    int slo = 0, shi = I;
    while (slo < shi) {
        const int mid = (slo + shi) >> 1;
        if (seg[mid] < jq) slo = mid + 1; else shi = mid;
    }
    const int lo0 = __shfl(slo, 0);
    const int hi0 = __shfl(slo, 1);
    int lo1 = 0, hi1 = 0;
    if (b1 < N) { lo1 = __shfl(slo, 2); hi1 = __shfl(slo, 3); }

    const int nt0 = (hi0 - lo0 + 31) >> 5;       // 32-row tiles
    const int nt1 = (hi1 - lo1 + 31) >> 5;
    const int total = nt0 + nt1;

    // Empty-bag zero writes.
    if (lane < 8) {
        if (nt0 == 0) xmil[(size_t)b0 * 8 + lane] = 0.f;
        if (b1 < N && nt1 == 0) xmil[(size_t)b1 * 8 + lane] = 0.f;
    }
    if (total == 0) return;

    // B fragments (weights), hi/lo split. B[k][n]: n=lane&15, k=(lane>>4)*8+j.
    const int bn  = lane & 15;
    const int bkg = lane >> 4;
    s8v BH[4], BL[4];
    const float* wcol = (bn < 8) ? (bu + bn) : (bz + (bn - 8));
#pragma unroll
    for (int kc = 0; kc < 4; ++kc) {
        float ws[8];
#pragma unroll
        for (int j = 0; j < 8; ++j)
            ws[j] = wcol[(size_t)(kc * 32 + bkg * 8 + j) * 8];
        split8(ws, BH[kc], BL[kc]);
    }

    float* const myXT = &XT[wv * 8192];       // my wave's 2 x 16KB buffers
    const int rl  = lane >> 5;                // row offset within 2-row group
    const int c4l = lane & 31;                // linear float4 col in LDS

    // chunk c params: bag0 tiles [0,nt0), bag1 tiles [nt0,total)
#define CH_BASE(C) (((C) >= nt0) ? (lo1 + (((C) - nt0) << 5)) : (lo0 + ((C) << 5)))
#define CH_LIM(C)  (((C) >= nt0) ? hi1 : hi0)

    // stage chunk C (32 rows) into buffer (C)&1 — exactly 16 load instructions
#define STAGE(C)                                                               \
    {                                                                          \
        const int base_ = CH_BASE(C);                                          \
        const int lim_  = CH_LIM(C);                                           \
        float* dst_ = &myXT[((C) & 1) * 4096];                                 \
        _Pragma("unroll")                                                      \
        for (int i = 0; i < 16; ++i) {                                         \
            const int r_ = i * 2 + rl;                                         \
            int grow_ = base_ + r_;                                            \
            if (grow_ >= lim_) grow_ = lim_ - 1;                               \
            const int c4g_ = c4l ^ (r_ & 7);                                   \
            const float* src_ = x + (size_t)grow_ * QDIM + 4 * (size_t)c4g_;   \
            __builtin_amdgcn_global_load_lds(                                  \
                (const __attribute__((address_space(1))) unsigned int*)src_,   \
                (__attribute__((address_space(3))) unsigned int*)              \
                    (dst_ + i * 256),                                          \
                16, 0, 0);                                                     \
        }                                                                      \
    }

    float lsum = 0.f, asum = 0.f;   // this lane's col partials (cols 0-7 only)

    const int am  = lane & 15;      // A/C row within a 16-row half
    const int akg = lane >> 4;
    const int sw  = am & 7;         // halves start at rows 0/16 (both ≡0 mod 8)

    STAGE(0);

    for (int c = 0; c < total; ++c) {
        if (c + 1 < total) {
            STAGE(c + 1);
            asm volatile("s_waitcnt vmcnt(16)" ::: "memory");
        } else {
            asm volatile("s_waitcnt vmcnt(0)" ::: "memory");
        }
        __builtin_amdgcn_sched_barrier(0);

        const float* buf = &myXT[(c & 1) * 4096];
        const int base = CH_BASE(c);
        const int lim  = CH_LIM(c);

#pragma unroll
        for (int h = 0; h < 2; ++h) {          // two 16-row halves
            const int lrow = h * 16 + am;

            f4v acc = {0.f, 0.f, 0.f, 0.f};
#pragma unroll
            for (int kc = 0; kc < 4; ++kc) {
                const int c4a = kc * 8 + akg * 2;
                const float4 xa = *(const float4*)&buf[lrow * QDIM + 4 * ((c4a    ) ^ sw)];
                const float4 xb = *(const float4*)&buf[lrow * QDIM + 4 * ((c4a + 1) ^ sw)];
                const float xs[8] = {xa.x, xa.y, xa.z, xa.w, xb.x, xb.y, xb.z, xb.w};
                s8v AH, AL;
                split8(xs, AH, AL);
                acc = __builtin_amdgcn_mfma_f32_16x16x32_bf16(AH, BH[kc], acc, 0, 0, 0);
                acc = __builtin_amdgcn_mfma_f32_16x16x32_bf16(AH, BL[kc], acc, 0, 0, 0);
                acc = __builtin_amdgcn_mfma_f32_16x16x32_bf16(AL, BH[kc], acc, 0, 0, 0);
            }

            // pool in-register: lane holds C rows h*16+(lane>>4)*4+i, col lane&15
            const int r0 = (lane >> 4) * 4;
#pragma unroll
            for (int i = 0; i < 4; ++i) {
                const float uv = acc[i];
                const float zv = __shfl_xor(uv, 8);   // col<8 lanes receive z
                const bool valid = (base + h * 16 + r0 + i) < lim;
                if ((lane & 15) < 8 && valid) {
                    const float e = __expf(uv);
                    lsum += e;
                    asum = fmaf(e, zv, asum);
                }
            }
        }

        // finalize a bag when its last tile was just pooled
        const bool fin0 = (c == nt0 - 1);
        const bool fin1 = (c == total - 1) && (nt1 > 0);
        if (fin0 || fin1) {
            float ls = lsum, as = asum;
            ls += __shfl_xor(ls, 16);
            as += __shfl_xor(as, 16);
            ls += __shfl_xor(ls, 32);
            as += __shfl_xor(as, 32);
            const int bag = fin0 ? b0 : b1;
            if (lane < 8)
                xmil[(size_t)bag * 8 + lane] = as / ls;
            lsum = 0.f; asum = 0.f;
        }
    }
#undef STAGE
#undef CH_BASE
#undef CH_LIM
}

// stats + output: per-block redundant stats over xmil (128 KB, L2/L3-hot).
__global__ __launch_bounds__(256) void mixmil_statsout(
    const float* __restrict__ xmil,
    const float* __restrict__ bz,
    int N, int total,
    float* __restrict__ out)
{
    double s[8], qq[8];
    float t2[8];
#pragma unroll
    for (int c = 0; c < 8; ++c) { s[c] = 0.0; qq[c] = 0.0; t2[c] = 0.f; }

    for (int r = threadIdx.x; r < N; r += 256) {
        const float* row = xmil + (size_t)r * 8;
#pragma unroll
        for (int c = 0; c < 8; ++c) {
            float v = row[c];
            s[c] += v;
            qq[c] += (double)v * (double)v;
        }
    }
    for (int r = threadIdx.x; r < QDIM; r += 256) {
        const float* row = bz + (size_t)r * 8;
#pragma unroll
        for (int c = 0; c < 8; ++c) { float v = row[c]; t2[c] = fmaf(v, v, t2[c]); }
    }

    for (int off = 32; off; off >>= 1) {
#pragma unroll
        for (int c = 0; c < 8; ++c) {
            s[c]  += __shfl_xor(s[c], off);
            qq[c] += __shfl_xor(qq[c], off);
            t2[c] += __shfl_xor(t2[c], off);
        }
    }

    __shared__ double S[4][8], QQ[4][8];
    __shared__ float T2[4][8];
    __shared__ float fb[8], fm[8], fr[8];
    const int w = threadIdx.x >> 6;
    if ((threadIdx.x & 63) == 0) {
#pragma unroll
        for (int c = 0; c < 8; ++c) { S[w][c] = s[c]; QQ[w][c] = qq[c]; T2[w][c] = t2[c]; }
    }
    __syncthreads();
    if (threadIdx.x < 8) {
        const int c = threadIdx.x;
        double ss = S[0][c] + S[1][c] + S[2][c] + S[3][c];
        double qs = QQ[0][c] + QQ[1][c] + QQ[2][c] + QQ[3][c];
        float  tt = T2[0][c] + T2[1][c] + T2[2][c] + T2[3][c];
        double mean = ss / (double)N;
        double var  = (qs - ss * ss / (double)N) / (double)(N - 1);
        fb[c] = sqrtf(tt / (float)QDIM);
        fm[c] = (float)mean;
        fr[c] = (float)(1.0 / sqrt(var));
    }
    __syncthreads();

    const int e = blockIdx.x * 256 + threadIdx.x;
    if (e < total) {
        const int c = e & 7;
        out[e] = fb[c] * (xmil[e] - fm[c]) * fr[c];
    }
}

extern "C" void kernel_launch(void* const* d_in, const int* in_sizes, int n_in,
                              void* d_out, int out_size, void* d_ws, size_t ws_size,
                              hipStream_t stream) {
    const float* x  = (const float*)d_in[0];
    const float* bu = (const float*)d_in[1];
    const float* bz = (const float*)d_in[2];
    const int*   sg = (const int*)d_in[3];   // sorted bag ids (int32)

    const int I = in_sizes[0] / QDIM;        // 512000
    const int N = out_size / C8;             // 4000 bags

    // grid: 2 bags per wave, 2 waves/block -> ceil(N/4) blocks (1000).
    const int nblk = (N + 3) / 4;            // 1000
    const int bstride = nblk * 2;            // 2000

    // ws layout: xmil[N*8]
    float* xmil = (float*)d_ws;

    mixmil_fused<<<nblk, 128, 0, stream>>>(x, bu, bz, sg, I, N, bstride, xmil);

    const int total = N * C8;
    mixmil_statsout<<<(total + 255) / 256, 256, 0, stream>>>(
        xmil, bz, N, total, (float*)d_out);
}

// Round 24
// 60.569 us; speedup vs baseline: 1.4457x; 1.1821x over previous
//
#include <hip/hip_runtime.h>
#include <hip/hip_bf16.h>

// MixMIL — R24 = revert to R19 (best: 61.0us). R23's 32-row chunks regressed
// (71.6us: 128-thr blocks + 64KB LDS -> 4 waves/CU, halved TLP). R19 is the
// measured optimum of this design space:
//   fused ~52us vs 42us x-read floor (~81% of 6.29 TB/s copy ceiling),
//   statsout ~4us, launch gap ~2-3us.
// Shapes: I=512000, Q=128, P=1, S=8, N=4000. x f32, betas f32, seg int32 sorted.
//
// Algebra: accumulate with raw beta_z; b = rms(beta_z) applied only at the end.
// Max-free softmax (|u|max ~62 << 88; verified R15-R19).
// 3-MFMA hi/lo bf16 split, hardware cvts (R17, absmax 1.56e-2).
// Structure: one bag per wave x 2 bags (persistent), per-wave 2x8KB LDS dbuf,
// global_load_lds(16B) pre-swizzled source cols, counted vmcnt(8), zero
// __syncthreads, in-register pooling via shfl_xor(8/16/32), in-wave
// binary-search bounds (lanes 0-3 parallel).

#define QDIM 128
#define C8 8

typedef __attribute__((ext_vector_type(8))) short s8v;
typedef __attribute__((ext_vector_type(4))) float f4v;

// hi/lo bf16 split via hardware conversions
__device__ __forceinline__ void split8(const float xs[8], s8v& AH, s8v& AL) {
#pragma unroll
    for (int j = 0; j < 8; ++j) {
        const float xv = xs[j];
        const __hip_bfloat16 hb = __float2bfloat16(xv);       // hw cvt (RNE)
        const float hf = __bfloat162float(hb);                // shift
        const __hip_bfloat16 lb = __float2bfloat16(xv - hf);  // exact residual cvt
        unsigned short hr, lr;
        __builtin_memcpy(&hr, &hb, 2);
        __builtin_memcpy(&lr, &lb, 2);
        AH[j] = (short)hr;
        AL[j] = (short)lr;
    }
}

__global__ __launch_bounds__(256) void mixmil_fused(
    const float* __restrict__ x,
    const float* __restrict__ bu,
    const float* __restrict__ bz,
    const int*   __restrict__ seg,
    int I, int N, int bstride,   // bstride = 4*gridDim
    float* __restrict__ xmil)    // [N,8]
{
    // 4 waves x 2 buffers x 8KB = 64KB
    __shared__ float XT[4 * 2 * 2048];

    const int t    = threadIdx.x;
    const int lane = t & 63;
    const int wv   = t >> 6;

    const int b0 = blockIdx.x * 4 + wv;          // first bag
    const int b1 = b0 + bstride;                 // second bag (may be >= N)
    if (b0 >= N) return;

    // In-wave bounds: lanes 0-3 binary-search seg for j = b0, b0+1, b1, b1+1.
    int jq = N;
    if (lane == 0) jq = b0;
    else if (lane == 1) jq = b0 + 1;
    else if (lane == 2) jq = (b1 < N) ? b1 : N;
    else if (lane == 3) jq = (b1 + 1 < N) ? (b1 + 1) : N;
    int slo = 0, shi = I;
    while (slo < shi) {
        const int mid = (slo + shi) >> 1;
        if (seg[mid] < jq) slo = mid + 1; else shi = mid;
    }
    const int lo0 = __shfl(slo, 0);
    const int hi0 = __shfl(slo, 1);
    int lo1 = 0, hi1 = 0;
    if (b1 < N) { lo1 = __shfl(slo, 2); hi1 = __shfl(slo, 3); }

    const int nt0 = (hi0 - lo0 + 15) >> 4;
    const int nt1 = (hi1 - lo1 + 15) >> 4;
    const int total = nt0 + nt1;

    // Empty-bag zero writes (finalize below only runs for bags with >=1 tile).
    if (lane < 8) {
        if (nt0 == 0) xmil[(size_t)b0 * 8 + lane] = 0.f;
        if (b1 < N && nt1 == 0) xmil[(size_t)b1 * 8 + lane] = 0.f;
    }
    if (total == 0) return;

    // B fragments (weights), hi/lo split via hw cvt. B[k][n]: n=lane&15, k=(lane>>4)*8+j.
    const int bn  = lane & 15;
    const int bkg = lane >> 4;
    s8v BH[4], BL[4];
    const float* wcol = (bn < 8) ? (bu + bn) : (bz + (bn - 8));
#pragma unroll
    for (int kc = 0; kc < 4; ++kc) {
        float ws[8];
#pragma unroll
        for (int j = 0; j < 8; ++j)
            ws[j] = wcol[(size_t)(kc * 32 + bkg * 8 + j) * 8];
        split8(ws, BH[kc], BL[kc]);
    }

    float* const myXT = &XT[wv * 4096];       // my wave's 2 buffers
    const int rl  = lane >> 5;                // row offset within 2-row group
    const int c4l = lane & 31;                // linear float4 col in LDS

    // chunk c params: bag0 tiles [0,nt0), bag1 tiles [nt0,total)
#define CH_BASE(C) (((C) >= nt0) ? (lo1 + (((C) - nt0) << 4)) : (lo0 + ((C) << 4)))
#define CH_LIM(C)  (((C) >= nt0) ? hi1 : hi0)

    // stage chunk C into buffer (C)&1 — always exactly 8 load instructions
#define STAGE(C)                                                               \
    {                                                                          \
        const int base_ = CH_BASE(C);                                          \
        const int lim_  = CH_LIM(C);                                           \
        float* dst_ = &myXT[((C) & 1) * 2048];                                 \
        _Pragma("unroll")                                                      \
        for (int i = 0; i < 8; ++i) {                                          \
            const int r_ = i * 2 + rl;                                         \
            int grow_ = base_ + r_;                                            \
            if (grow_ >= lim_) grow_ = lim_ - 1;                               \
            const int c4g_ = c4l ^ (r_ & 7);                                   \
            const float* src_ = x + (size_t)grow_ * QDIM + 4 * (size_t)c4g_;   \
            __builtin_amdgcn_global_load_lds(                                  \
                (const __attribute__((address_space(1))) unsigned int*)src_,   \
                (__attribute__((address_space(3))) unsigned int*)              \
                    (dst_ + i * 256),                                          \
                16, 0, 0);                                                     \
        }                                                                      \
    }

    float lsum = 0.f, asum = 0.f;   // this lane's col partials (cols 0-7 only)

    const int am  = lane & 15;      // my A/C row within tile
    const int akg = lane >> 4;
    const int sw  = am & 7;

    STAGE(0);

    for (int c = 0; c < total; ++c) {
        if (c + 1 < total) {
            STAGE(c + 1);
            asm volatile("s_waitcnt vmcnt(8)" ::: "memory");
        } else {
            asm volatile("s_waitcnt vmcnt(0)" ::: "memory");
        }
        __builtin_amdgcn_sched_barrier(0);

        const float* buf = &myXT[(c & 1) * 2048];

        f4v acc = {0.f, 0.f, 0.f, 0.f};
#pragma unroll
        for (int kc = 0; kc < 4; ++kc) {
            const int c4a = kc * 8 + akg * 2;
            const float4 xa = *(const float4*)&buf[am * QDIM + 4 * ((c4a    ) ^ sw)];
            const float4 xb = *(const float4*)&buf[am * QDIM + 4 * ((c4a + 1) ^ sw)];
            const float xs[8] = {xa.x, xa.y, xa.z, xa.w, xb.x, xb.y, xb.z, xb.w};
            s8v AH, AL;
            split8(xs, AH, AL);
            acc = __builtin_amdgcn_mfma_f32_16x16x32_bf16(AH, BH[kc], acc, 0, 0, 0);
            acc = __builtin_amdgcn_mfma_f32_16x16x32_bf16(AH, BL[kc], acc, 0, 0, 0);
            acc = __builtin_amdgcn_mfma_f32_16x16x32_bf16(AL, BH[kc], acc, 0, 0, 0);
        }

        // pool in-register: lane holds C rows (lane>>4)*4+i, col lane&15.
        const int base = CH_BASE(c);
        const int lim  = CH_LIM(c);
        const int r0   = (lane >> 4) * 4;
#pragma unroll
        for (int i = 0; i < 4; ++i) {
            const float uv = acc[i];
            const float zv = __shfl_xor(uv, 8);       // col<8 lanes receive z
            const bool valid = (base + r0 + i) < lim;
            if ((lane & 15) < 8 && valid) {
                const float e = __expf(uv);
                lsum += e;
                asum = fmaf(e, zv, asum);
            }
        }

        // finalize a bag when its last tile was just pooled
        const bool fin0 = (c == nt0 - 1);
        const bool fin1 = (c == total - 1) && (nt1 > 0);
        if (fin0 || fin1) {
            float ls = lsum, as = asum;
            ls += __shfl_xor(ls, 16);
            as += __shfl_xor(as, 16);
            ls += __shfl_xor(ls, 32);
            as += __shfl_xor(as, 32);
            const int bag = fin0 ? b0 : b1;
            if (lane < 8)
                xmil[(size_t)bag * 8 + lane] = as / ls;
            lsum = 0.f; asum = 0.f;
        }
    }
#undef STAGE
#undef CH_BASE
#undef CH_LIM
}

// stats + output: per-block redundant stats over xmil (128 KB, L2/L3-hot).
__global__ __launch_bounds__(256) void mixmil_statsout(
    const float* __restrict__ xmil,
    const float* __restrict__ bz,
    int N, int total,
    float* __restrict__ out)
{
    double s[8], qq[8];
    float t2[8];
#pragma unroll
    for (int c = 0; c < 8; ++c) { s[c] = 0.0; qq[c] = 0.0; t2[c] = 0.f; }

    for (int r = threadIdx.x; r < N; r += 256) {
        const float* row = xmil + (size_t)r * 8;
#pragma unroll
        for (int c = 0; c < 8; ++c) {
            float v = row[c];
            s[c] += v;
            qq[c] += (double)v * (double)v;
        }
    }
    for (int r = threadIdx.x; r < QDIM; r += 256) {
        const float* row = bz + (size_t)r * 8;
#pragma unroll
        for (int c = 0; c < 8; ++c) { float v = row[c]; t2[c] = fmaf(v, v, t2[c]); }
    }

    for (int off = 32; off; off >>= 1) {
#pragma unroll
        for (int c = 0; c < 8; ++c) {
            s[c]  += __shfl_xor(s[c], off);
            qq[c] += __shfl_xor(qq[c], off);
            t2[c] += __shfl_xor(t2[c], off);
        }
    }

    __shared__ double S[4][8], QQ[4][8];
    __shared__ float T2[4][8];
    __shared__ float fb[8], fm[8], fr[8];
    const int w = threadIdx.x >> 6;
    if ((threadIdx.x & 63) == 0) {
#pragma unroll
        for (int c = 0; c < 8; ++c) { S[w][c] = s[c]; QQ[w][c] = qq[c]; T2[w][c] = t2[c]; }
    }
    __syncthreads();
    if (threadIdx.x < 8) {
        const int c = threadIdx.x;
        double ss = S[0][c] + S[1][c] + S[2][c] + S[3][c];
        double qs = QQ[0][c] + QQ[1][c] + QQ[2][c] + QQ[3][c];
        float  tt = T2[0][c] + T2[1][c] + T2[2][c] + T2[3][c];
        double mean = ss / (double)N;
        double var  = (qs - ss * ss / (double)N) / (double)(N - 1);
        fb[c] = sqrtf(tt / (float)QDIM);
        fm[c] = (float)mean;
        fr[c] = (float)(1.0 / sqrt(var));
    }
    __syncthreads();

    const int e = blockIdx.x * 256 + threadIdx.x;
    if (e < total) {
        const int c = e & 7;
        out[e] = fb[c] * (xmil[e] - fm[c]) * fr[c];
    }
}

extern "C" void kernel_launch(void* const* d_in, const int* in_sizes, int n_in,
                              void* d_out, int out_size, void* d_ws, size_t ws_size,
                              hipStream_t stream) {
    const float* x  = (const float*)d_in[0];
    const float* bu = (const float*)d_in[1];
    const float* bz = (const float*)d_in[2];
    const int*   sg = (const int*)d_in[3];   // sorted bag ids (int32)

    const int I = in_sizes[0] / QDIM;        // 512000
    const int N = out_size / C8;             // 4000 bags

    // grid: 2 bags per wave -> ceil(N/8) blocks; all co-resident (<=512).
    const int nblk = (N + 7) / 8;            // 500
    const int bstride = nblk * 4;            // 2000

    // ws layout: xmil[N*8]
    float* xmil = (float*)d_ws;

    mixmil_fused<<<nblk, 256, 0, stream>>>(x, bu, bz, sg, I, N, bstride, xmil);

    const int total = N * C8;
    mixmil_statsout<<<(total + 255) / 256, 256, 0, stream>>>(
        xmil, bz, N, total, (float*)d_out);
}